// Round 1
// baseline (374.467 us; speedup 1.0000x reference)
//
#include <hip/hip_runtime.h>
#include <hip/hip_bf16.h>
#include <stdint.h>

// ---- problem constants ----
#define B64   64
#define DIMS  120
#define NLOC  (DIMS*DIMS)      // 14400 V1 locations
#define V4D   29
#define NLOC4 (V4D*V4D)        // 841 V4 locations
#define SWROW 81               // 9x9 patch

typedef __attribute__((ext_vector_type(8))) short bf16x8;  // 8 bf16 in 4 VGPRs
typedef __attribute__((ext_vector_type(4))) float f32x4;

__device__ __forceinline__ unsigned short f2bf(float f) {
    unsigned u = __float_as_uint(f);
    u += 0x7fffu + ((u >> 16) & 1u);   // round-to-nearest-even
    return (unsigned short)(u >> 16);
}

// ------------------------------------------------------------------
// k0: replicate x (fp32 [64][128][128]) into bf16 column-major groups:
// xrep[r][b][col][g][q] = x[b][8g + r + q][col]  (0 if row >= 128)
// so that rows (i+8h .. i+8h+7) at a column are one aligned 16B load
// with r = i&7, g = (i>>3)+h.
// ------------------------------------------------------------------
__global__ __launch_bounds__(256) void k0_xrep(const float* __restrict__ x,
                                               unsigned short* __restrict__ xrep) {
    int n = blockIdx.x * 256 + threadIdx.x;      // 8*64*16*128 = 1048576 tasks
    int col = n & 127;
    int g   = (n >> 7) & 15;
    int b   = (n >> 11) & 63;
    int r   = (n >> 17) & 7;
    int row0 = 8 * g + r;
    bf16x8 pk;
#pragma unroll
    for (int q = 0; q < 8; ++q) {
        int row = row0 + q;
        float f = (row < 128) ? x[(b * 128 + row) * 128 + col] : 0.0f;
        pk[q] = (short)f2bf(f);
    }
    size_t off = ((size_t)(((r * 64 + b) * 128 + col) * 16 + g)) * 8;
    *(bf16x8*)(xrep + off) = pk;
}

// ------------------------------------------------------------------
// k1: V1 locally-connected layer + relu + phase-mean, MFMA 16x16x32 bf16.
// One wave per location. Per location: C[64b x 32c] = patches x weights^T.
// K mapped column-major: k = kw*16 + kh (kw 0..9 padded, kh 0..15 padded),
// K = 160 -> 5 K-steps. Pad positions have B (weights) = 0, A garbage-safe.
// A-frag: lane l: m=b=(l&15)+16mt, k-chunk t=l>>4 -> kw=2ks+(t>>1), kh=8(t&1)+j
//   -> one global_load_dwordx4 from xrep.
// B-frag: 8 strided scalar fp32 loads (stride 36B) from simple_weight,
//   masked to 0 for kh>8 or kw>8, addresses clamped in-bounds.
// Epilogue: relu -> mean over 4 phases via per-wave LDS pool, store bf16
// cplx[loc][b][s] (8 contiguous bf16 per b = 16B store).
// ------------------------------------------------------------------
__global__ __launch_bounds__(256, 4) void k1_v1(const unsigned short* __restrict__ xrep,
                                                const float* __restrict__ sw,
                                                unsigned short* __restrict__ cplx) {
    __shared__ float pool[4][64][33];   // per-wave scratch, padded stride 33
    int tid = threadIdx.x;
    int w = tid >> 6, l = tid & 63;
    int loc = blockIdx.x * 4 + w;       // grid 3600 * 4 waves = 14400
    int i = loc / DIMS, j = loc - i * DIMS;
    int r = i & 7, gbase = i >> 3;

    int ln = l & 15, t = l >> 4;
    int h = t & 1, kwoff = t >> 1;

    f32x4 acc[4][2];
#pragma unroll
    for (int mt = 0; mt < 4; ++mt)
#pragma unroll
        for (int nt = 0; nt < 2; ++nt)
            acc[mt][nt] = (f32x4){0.f, 0.f, 0.f, 0.f};

#pragma unroll
    for (int ks = 0; ks < 5; ++ks) {
        int kw = 2 * ks + kwoff;              // 0..9 (9 = pad column)
        // ---- A fragments (4 M-tiles), one dwordx4 each ----
        int col = j + kw; col = (col > 127) ? 127 : col;   // clamp (kw=9 pad)
        int g = gbase + h;                     // <= 15 by construction
        bf16x8 a[4];
#pragma unroll
        for (int mt = 0; mt < 4; ++mt) {
            int b = ln + 16 * mt;
            size_t off = ((size_t)(((r * 64 + b) * 128 + col) * 16 + g)) * 8;
            a[mt] = *(const bf16x8*)(xrep + off);
        }
        // ---- B fragments (2 N-tiles) ----
        bool m0 = (kw < 9);           // valid column
        bool m1 = m0 && (h == 0);     // valid for j>=1 elements (kh=8h+j<=8)
        bf16x8 bfr[2];
#pragma unroll
        for (int nt = 0; nt < 2; ++nt) {
            int c = ln + 16 * nt;
            const float* base = sw + ((size_t)c * NLOC + loc) * SWROW + 72 * h + kw;
            const float* pA = m0 ? base : sw;   // clamp addr for masked lanes
            const float* pB = m1 ? base : sw;
            bf16x8 bb;
            {
                float f0 = pA[0];
                bb[0] = (short)f2bf(m0 ? f0 : 0.0f);
            }
#pragma unroll
            for (int jj = 1; jj < 8; ++jj) {
                float fj = pB[9 * jj];          // e = (8h+jj)*9 + kw
                bb[jj] = (short)f2bf(m1 ? fj : 0.0f);
            }
            bfr[nt] = bb;
        }
        // ---- MFMAs ----
#pragma unroll
        for (int mt = 0; mt < 4; ++mt)
#pragma unroll
            for (int nt = 0; nt < 2; ++nt)
                acc[mt][nt] = __builtin_amdgcn_mfma_f32_16x16x32_bf16(
                    a[mt], bfr[nt], acc[mt][nt], 0, 0, 0);
    }

    // ---- epilogue: relu, write C to pool, phase-mean, bf16 store ----
#pragma unroll
    for (int mt = 0; mt < 4; ++mt)
#pragma unroll
        for (int nt = 0; nt < 2; ++nt)
#pragma unroll
            for (int reg = 0; reg < 4; ++reg) {
                int brow = 16 * mt + 4 * t + reg;   // C row = b
                int ccol = 16 * nt + ln;            // C col = c
                pool[w][brow][ccol] = fmaxf(acc[mt][nt][reg], 0.0f);
            }
    __syncthreads();
    bf16x8 po;
#pragma unroll
    for (int s = 0; s < 8; ++s) {
        float m = 0.25f * (pool[w][l][4 * s] + pool[w][l][4 * s + 1] +
                           pool[w][l][4 * s + 2] + pool[w][l][4 * s + 3]);
        po[s] = (short)f2bf(m);
    }
    *(bf16x8*)(cplx + (size_t)loc * 512 + l * 8) = po;   // [loc][b=l][s]
}

// ------------------------------------------------------------------
// k2: V4 locally-connected pooling, MFMA 16x16x32 bf16, one wave/location.
// C[64b x 16o] with K = 512 = (pos 0..63) * 8 + (s 0..7), 16 K-steps.
// A-frag: cplx[iloc(pos)][b][s0..7] = one aligned 16B global load.
// B-frag: 8 strided scalar fp32 loads from v4_weight, converted inline.
// Output v4s fp32 [loc][b][o].
// ------------------------------------------------------------------
__global__ __launch_bounds__(256, 4) void k2_v4(const unsigned short* __restrict__ cplx,
                                                const float* __restrict__ vw,
                                                float* __restrict__ v4s) {
    int tid = threadIdx.x;
    int w = tid >> 6, l = tid & 63;
    int loc = blockIdx.x * 4 + w;       // grid 211 -> 844 waves, 3 idle
    if (loc >= NLOC4) return;
    int oi = loc / V4D, oj = loc - oi * V4D;
    int ln = l & 15, t = l >> 4;

    f32x4 acc[4];
#pragma unroll
    for (int mt = 0; mt < 4; ++mt) acc[mt] = (f32x4){0.f, 0.f, 0.f, 0.f};

#pragma unroll
    for (int ks = 0; ks < 16; ++ks) {
        int pos = 4 * ks + t;                 // 0..63
        int kh = pos >> 3, kw = pos & 7;
        int iloc = (oi * 4 + kh) * DIMS + (oj * 4 + kw);
        // A fragments
        const unsigned short* ab = cplx + (size_t)iloc * 512 + ln * 8;
        bf16x8 a[4];
#pragma unroll
        for (int mt = 0; mt < 4; ++mt)
            a[mt] = *(const bf16x8*)(ab + mt * 128);   // b-stride 16*8 elems
        // B fragment: o = ln, elements s = 0..7
        const float* wb = vw + ((size_t)(ln * 8) * NLOC4 + loc) * 64 + pos;
        bf16x8 bb;
#pragma unroll
        for (int s = 0; s < 8; ++s)
            bb[s] = (short)f2bf(wb[(size_t)s * NLOC4 * 64]);
#pragma unroll
        for (int mt = 0; mt < 4; ++mt)
            acc[mt] = __builtin_amdgcn_mfma_f32_16x16x32_bf16(a[mt], bb, acc[mt], 0, 0, 0);
    }
#pragma unroll
    for (int mt = 0; mt < 4; ++mt)
#pragma unroll
        for (int reg = 0; reg < 4; ++reg) {
            int b = 16 * mt + 4 * t + reg;
            v4s[(size_t)loc * 1024 + b * 16 + ln] = acc[mt][reg];
        }
}

// ------------------------------------------------------------------
// k3: decision readout. One block per batch element.
// out[b][d] = sum_{o,loc} v4s[loc][b][o] * dw[d][o*841+loc] + db[d]
// ------------------------------------------------------------------
__global__ __launch_bounds__(256) void k3_dec(const float* __restrict__ v4s,
                                              const float* __restrict__ dw,
                                              const float* __restrict__ db,
                                              float* __restrict__ out) {
    int b = blockIdx.x, tid = threadIdx.x;
    float a0 = 0.f, a1 = 0.f;
    for (int loc = tid; loc < NLOC4; loc += 256) {
        const float* vp = v4s + (size_t)loc * 1024 + b * 16;
#pragma unroll
        for (int o4 = 0; o4 < 4; ++o4) {
            f32x4 v = *(const f32x4*)(vp + o4 * 4);
#pragma unroll
            for (int q = 0; q < 4; ++q) {
                int o = o4 * 4 + q;
                a0 += v[q] * dw[o * NLOC4 + loc];
                a1 += v[q] * dw[16 * NLOC4 + o * NLOC4 + loc];
            }
        }
    }
    __shared__ float r0[256], r1[256];
    r0[tid] = a0; r1[tid] = a1;
    __syncthreads();
    for (int s = 128; s > 0; s >>= 1) {
        if (tid < s) { r0[tid] += r0[tid + s]; r1[tid] += r1[tid + s]; }
        __syncthreads();
    }
    if (tid == 0) {
        out[2 * b + 0] = r0[0] + db[0];
        out[2 * b + 1] = r1[0] + db[1];
    }
}

// ------------------------------------------------------------------
extern "C" void kernel_launch(void* const* d_in, const int* in_sizes, int n_in,
                              void* d_out, int out_size, void* d_ws, size_t ws_size,
                              hipStream_t stream) {
    const float* x  = (const float*)d_in[0];   // [64][1][128][128]
    const float* sw = (const float*)d_in[1];   // [32][120][120][81]
    const float* vw = (const float*)d_in[2];   // [16][8][29][29][64]
    const float* dw = (const float*)d_in[3];   // [2][13456]
    const float* db = (const float*)d_in[4];   // [2]
    float* out = (float*)d_out;                // [64][2]

    char* ws = (char*)d_ws;
    // workspace layout (all 256B-aligned offsets):
    unsigned short* xrep = (unsigned short*)ws;                      // 16,777,216 B
    unsigned short* cplx = (unsigned short*)(ws + 16777216);         // 14,745,600 B
    float*          v4s  = (float*)(ws + 16777216 + 14745600);       //  3,444,736 B

    k0_xrep<<<4096, 256, 0, stream>>>(x, xrep);
    k1_v1<<<NLOC / 4, 256, 0, stream>>>(xrep, sw, cplx);
    k2_v4<<<(NLOC4 + 3) / 4, 256, 0, stream>>>(cplx, vw, v4s);
    k3_dec<<<B64, 256, 0, stream>>>(v4s, dw, db, out);
}

// Round 2
// 286.734 us; speedup vs baseline: 1.3060x; 1.3060x over previous
//
#include <hip/hip_runtime.h>
#include <hip/hip_bf16.h>
#include <stdint.h>

// ---- problem constants ----
#define B64   64
#define DIMS  120
#define NLOC  (DIMS*DIMS)      // 14400 V1 locations
#define V4D   29
#define NLOC4 (V4D*V4D)        // 841 V4 locations

typedef __attribute__((ext_vector_type(8))) short bf16x8;  // 8 bf16 in 4 VGPRs
typedef __attribute__((ext_vector_type(4))) float f32x4;

__device__ __forceinline__ unsigned short f2bf(float f) {
    unsigned u = __float_as_uint(f);
    u += 0x7fffu + ((u >> 16) & 1u);   // round-to-nearest-even
    return (unsigned short)(u >> 16);
}

// ------------------------------------------------------------------
// k0: pack x into two bf16 replica tensors with b innermost for coalesced
// MFMA A-fragment loads (16 lanes x 16B = 256B contiguous per quarter):
//   xrep [r][col][g][b][q]  = x[b][8g+r+q][col]   (rows chunked)
//   xrepT[rc][row][gc][b][q] = x[b][row][8gc+rc+q] (cols chunked)
// Zero-filled past the 128 edge. LDS tile transpose: coalesced global reads
// (lanes~cols), coalesced global writes (lanes~b).
// Grid: 256 blocks = 128 xrep (g, colblk) + 128 xrepT (gc, rowblk).
// ------------------------------------------------------------------
__global__ __launch_bounds__(256) void k0_pack(const float* __restrict__ x,
                                               unsigned short* __restrict__ xrep,
                                               unsigned short* __restrict__ xrepT) {
    __shared__ unsigned short tile[16 * 16 * 64];   // [d1][d2][b]
    int blk = blockIdx.x;
    int isT = (blk >= 128) ? 1 : 0;
    int b2 = blk - 128 * isT;
    int g = b2 >> 3;             // chunk index 0..15
    int fb = (b2 & 7) << 4;      // fixed-dim block base (col for xrep, row for xrepT)
    int tid = threadIdx.x;
    int bb = tid >> 2, c4 = (tid & 3) << 2;
    // ---- stage 16x16x64 window, converting to bf16 ----
#pragma unroll 4
    for (int rr = 0; rr < 16; ++rr) {
        int row, col;
        if (!isT) { row = 8 * g + rr; col = fb + c4; }
        else      { row = fb + rr;    col = 8 * g + c4; }
        f32x4 v;
        if (row < 128 && col < 128)
            v = *(const f32x4*)(x + ((size_t)bb * 128 + row) * 128 + col);
        else
            v = (f32x4){0.f, 0.f, 0.f, 0.f};
#pragma unroll
        for (int cc = 0; cc < 4; ++cc) {
            int d1 = isT ? rr : (c4 + cc);
            int d2 = isT ? (c4 + cc) : rr;
            tile[(d1 * 16 + d2) * 64 + bb] = f2bf(v[cc]);
        }
    }
    __syncthreads();
    // ---- pack: 8192 chunks of 16B, lanes vary b (coalesced 1KB stores) ----
    unsigned short* outp = isT ? xrepT : xrep;
    int b = tid & 63;
#pragma unroll
    for (int it = 0; it < 32; ++it) {
        int u = (it * 256 + tid) >> 6;   // 0..127
        int d1 = u & 15, rq = u >> 4;    // rq = r (or rc), 0..7
        bf16x8 pk;
#pragma unroll
        for (int q = 0; q < 8; ++q)
            pk[q] = (short)tile[(d1 * 16 + rq + q) * 64 + b];
        size_t off = ((((size_t)rq * 128 + (fb + d1)) * 16 + g) * 64 + b) * 8;
        *(bf16x8*)(outp + off) = pk;
    }
}

// ------------------------------------------------------------------
// k1: V1 locally-connected + relu + phase-mean. One wave per location,
// 4 consecutive locations per block (same i row: 120 % 4 == 0).
// K = 96 (3 MFMA K-steps), chunk ch = ks*4 + t:
//   ch 0..8 : patch col kw=ch, rows i..i+7   -> xrep  (kh = jj)
//   ch 9    : row i+8, cols j..j+7           -> xrepT (kw = jj)
//   ch 10   : row i+8, col j+8 (jj==0 only)  -> xrepT at gc+1
//   ch 11   : pad (B = 0)
// B staged per-block: sw fp32 -> LDS bf16 [w][c][82] (coalesced global reads).
// Epilogue: relu -> shfl_xor phase mean -> 9KB LDS transpose -> bf16
// cplx[loc][b][s] 16B coalesced stores.
// ------------------------------------------------------------------
__global__ __launch_bounds__(256) void k1_v1(const unsigned short* __restrict__ xrep,
                                             const unsigned short* __restrict__ xrepT,
                                             const float* __restrict__ sw,
                                             unsigned short* __restrict__ cplx) {
    __shared__ __align__(16) char smraw[4 * 32 * 82 * 2];   // 20992 B
    unsigned short* stage = (unsigned short*)smraw;          // [w][c][82] bf16
    float* pool2 = (float*)smraw;                            // [w][64][9] fp32 (9216 B, overlaid)

    int tid = threadIdx.x;
    int blk = blockIdx.x;
    int blk2 = (blk & 7) * 450 + (blk >> 3);   // XCD band swizzle (3600 = 8*450)
    int loc0 = blk2 * 4;

    // ---- stage simple_weight for 4 locations: 2592 dwordx4, coalesced ----
#pragma unroll
    for (int it = 0; it < 11; ++it) {
        int idx = it * 256 + tid;
        if (idx < 2592) {
            int c = idx / 81, r4 = idx - c * 81;
            f32x4 v = *(const f32x4*)(sw + ((size_t)c * NLOC + loc0) * 81 + r4 * 4);
            int posf = r4 * 4;
#pragma unroll
            for (int qq = 0; qq < 4; ++qq) {
                int pp = posf + qq;          // 0..323 = w*81 + e
                int w2 = 0, e2 = pp;
                if (e2 >= 162) { w2 = 2; e2 -= 162; }
                if (e2 >= 81)  { w2 += 1; e2 -= 81; }
                stage[(w2 * 32 + c) * 82 + e2] = f2bf(v[qq]);
            }
        }
    }
    __syncthreads();

    int w = tid >> 6, l = tid & 63;
    int loc = loc0 + w;
    int i = loc / DIMS, j = loc - i * DIMS;
    int ln = l & 15, t = l >> 4;
    int r = i & 7, g = i >> 3, rc = j & 7, gc = j >> 3;
    const unsigned short* stw = stage + w * 32 * 82;

    f32x4 acc[4][2];
#pragma unroll
    for (int mt = 0; mt < 4; ++mt)
#pragma unroll
        for (int nt = 0; nt < 2; ++nt)
            acc[mt][nt] = (f32x4){0.f, 0.f, 0.f, 0.f};

#pragma unroll
    for (int ks = 0; ks < 3; ++ks) {
        int ch = ks * 4 + t;
        // ---- A fragments ----
        const unsigned short* abase;
        if (ks < 2) {
            int col = j + ch;    // ch <= 7 here
            abase = xrep + (((size_t)r * 128 + col) * 16 + g) * 512;
        } else {
            const unsigned short* a0 = xrep + (((size_t)r * 128 + (j + 8)) * 16 + g) * 512;
            int gc2 = gc + ((t >= 2) ? 1 : 0);
            const unsigned short* a1 = xrepT + (((size_t)rc * 128 + (i + 8)) * 16 + gc2) * 512;
            abase = (t == 0) ? a0 : a1;
        }
        bf16x8 a[4];
#pragma unroll
        for (int mt = 0; mt < 4; ++mt)
            a[mt] = *(const bf16x8*)(abase + (size_t)(ln + 16 * mt) * 8);
        // ---- B fragments from LDS ----
        bf16x8 bfr[2];
#pragma unroll
        for (int nt = 0; nt < 2; ++nt) {
            const unsigned short* sc = stw + (ln + 16 * nt) * 82;
#pragma unroll
            for (int jj = 0; jj < 8; ++jj) {
                unsigned short v;
                if (ks < 2) {
                    v = sc[jj * 9 + ch];
                } else {
                    int e = (t == 0) ? (jj * 9 + 8) : ((t == 1) ? (72 + jj) : 80);
                    bool valid = (t <= 1) || (t == 2 && jj == 0);
                    v = valid ? sc[e] : (unsigned short)0;
                }
                bfr[nt][jj] = (short)v;
            }
        }
        // ---- MFMAs ----
#pragma unroll
        for (int mt = 0; mt < 4; ++mt)
#pragma unroll
            for (int nt = 0; nt < 2; ++nt)
                acc[mt][nt] = __builtin_amdgcn_mfma_f32_16x16x32_bf16(
                    a[mt], bfr[nt], acc[mt][nt], 0, 0, 0);
    }

    // ---- epilogue: relu, phase-mean via shfl_xor, LDS transpose, store ----
    __syncthreads();                     // stage dead; pool2 overlays it
    float* pl = pool2 + w * 64 * 9;
#pragma unroll
    for (int mt = 0; mt < 4; ++mt)
#pragma unroll
        for (int nt = 0; nt < 2; ++nt)
#pragma unroll
            for (int reg = 0; reg < 4; ++reg) {
                float v = fmaxf(acc[mt][nt][reg], 0.0f);
                v += __shfl_xor(v, 1, 64);
                v += __shfl_xor(v, 2, 64);
                if ((ln & 3) == 0) {
                    int b = 16 * mt + 4 * t + reg;
                    int s = 4 * nt + (ln >> 2);
                    pl[b * 9 + s] = v * 0.25f;
                }
            }
    __syncthreads();
    bf16x8 po;
#pragma unroll
    for (int s = 0; s < 8; ++s)
        po[s] = (short)f2bf(pl[l * 9 + s]);
    *(bf16x8*)(cplx + (size_t)loc * 512 + l * 8) = po;
}

// ------------------------------------------------------------------
// k2: V4 pooling. One block per location; vw slice (128x64 fp32) staged in
// LDS (row-stride 65 to break bank conflicts); 4 waves split K (4 MFMA
// K-steps each), LDS reduce across waves. A from cplx: coalesced 16B loads.
// ------------------------------------------------------------------
__global__ __launch_bounds__(256) void k2_v4(const unsigned short* __restrict__ cplx,
                                             const float* __restrict__ vw,
                                             float* __restrict__ v4s) {
    __shared__ __align__(16) char smraw[128 * 65 * 4];   // 33280 B
    float* stg = (float*)smraw;                          // [128][65]
    float* pool = (float*)smraw;                         // [4][64][16] (16KB, overlaid)

    int tid = threadIdx.x;
    int blk = blockIdx.x;
    int loc = (blk < 840) ? ((blk & 7) * 105 + (blk >> 3)) : 840;  // XCD band swizzle
    int oi = loc / V4D, oj = loc - oi * V4D;

    // ---- stage vw[.,.,loc,.]: 2048 dwordx4 coalesced ----
#pragma unroll
    for (int it = 0; it < 8; ++it) {
        int idx = it * 256 + tid;
        int row = idx >> 4, p4 = (idx & 15) * 4;
        f32x4 v = *(const f32x4*)(vw + ((size_t)row * NLOC4 + loc) * 64 + p4);
#pragma unroll
        for (int qq = 0; qq < 4; ++qq)
            stg[row * 65 + p4 + qq] = v[qq];
    }
    __syncthreads();

    int w = tid >> 6, l = tid & 63;
    int ln = l & 15, t = l >> 4;
    f32x4 acc[4];
#pragma unroll
    for (int mt = 0; mt < 4; ++mt) acc[mt] = (f32x4){0.f, 0.f, 0.f, 0.f};

#pragma unroll
    for (int kk = 0; kk < 4; ++kk) {
        int ksg = w * 4 + kk;
        int pos = 4 * ksg + t;               // 0..63
        int kh = pos >> 3, kw = pos & 7;
        int iloc = (oi * 4 + kh) * DIMS + oj * 4 + kw;
        const unsigned short* ab = cplx + (size_t)iloc * 512 + ln * 8;
        bf16x8 a[4];
#pragma unroll
        for (int mt = 0; mt < 4; ++mt)
            a[mt] = *(const bf16x8*)(ab + mt * 128);
        bf16x8 bb;
#pragma unroll
        for (int jj = 0; jj < 8; ++jj)
            bb[jj] = (short)f2bf(stg[(ln * 8 + jj) * 65 + pos]);
#pragma unroll
        for (int mt = 0; mt < 4; ++mt)
            acc[mt] = __builtin_amdgcn_mfma_f32_16x16x32_bf16(a[mt], bb, acc[mt], 0, 0, 0);
    }
    __syncthreads();                       // stg dead; pool overlays
#pragma unroll
    for (int mt = 0; mt < 4; ++mt)
#pragma unroll
        for (int reg = 0; reg < 4; ++reg)
            pool[((w * 64) + 16 * mt + 4 * t + reg) * 16 + ln] = acc[mt][reg];
    __syncthreads();
    int o = tid & 15, brow = tid >> 4;
#pragma unroll
    for (int itb = 0; itb < 4; ++itb) {
        int b = brow + 16 * itb;
        float s = pool[(0 * 64 + b) * 16 + o] + pool[(1 * 64 + b) * 16 + o] +
                  pool[(2 * 64 + b) * 16 + o] + pool[(3 * 64 + b) * 16 + o];
        v4s[(size_t)loc * 1024 + b * 16 + o] = s;
    }
}

// ------------------------------------------------------------------
// k3: decision readout. One block per batch element.
// ------------------------------------------------------------------
__global__ __launch_bounds__(256) void k3_dec(const float* __restrict__ v4s,
                                              const float* __restrict__ dw,
                                              const float* __restrict__ db,
                                              float* __restrict__ out) {
    int b = blockIdx.x, tid = threadIdx.x;
    float a0 = 0.f, a1 = 0.f;
    for (int loc = tid; loc < NLOC4; loc += 256) {
        const float* vp = v4s + (size_t)loc * 1024 + b * 16;
#pragma unroll
        for (int o4 = 0; o4 < 4; ++o4) {
            f32x4 v = *(const f32x4*)(vp + o4 * 4);
#pragma unroll
            for (int q = 0; q < 4; ++q) {
                int o = o4 * 4 + q;
                a0 += v[q] * dw[o * NLOC4 + loc];
                a1 += v[q] * dw[16 * NLOC4 + o * NLOC4 + loc];
            }
        }
    }
    __shared__ float r0[256], r1[256];
    r0[tid] = a0; r1[tid] = a1;
    __syncthreads();
    for (int s = 128; s > 0; s >>= 1) {
        if (tid < s) { r0[tid] += r0[tid + s]; r1[tid] += r1[tid + s]; }
        __syncthreads();
    }
    if (tid == 0) {
        out[2 * b + 0] = r0[0] + db[0];
        out[2 * b + 1] = r1[0] + db[1];
    }
}

// ------------------------------------------------------------------
extern "C" void kernel_launch(void* const* d_in, const int* in_sizes, int n_in,
                              void* d_out, int out_size, void* d_ws, size_t ws_size,
                              hipStream_t stream) {
    const float* x  = (const float*)d_in[0];   // [64][1][128][128]
    const float* sw = (const float*)d_in[1];   // [32][120][120][81]
    const float* vw = (const float*)d_in[2];   // [16][8][29][29][64]
    const float* dw = (const float*)d_in[3];   // [2][13456]
    const float* db = (const float*)d_in[4];   // [2]
    float* out = (float*)d_out;                // [64][2]

    char* ws = (char*)d_ws;
    unsigned short* xrep  = (unsigned short*)ws;                         // 16,777,216 B
    unsigned short* xrepT = (unsigned short*)(ws + 16777216);            // 16,777,216 B
    unsigned short* cplx  = (unsigned short*)(ws + 33554432);            // 14,745,600 B
    float*          v4s   = (float*)(ws + 48300032);                     //  3,444,736 B

    k0_pack<<<256, 256, 0, stream>>>(x, xrep, xrepT);
    k1_v1<<<NLOC / 4, 256, 0, stream>>>(xrep, xrepT, sw, cplx);
    k2_v4<<<NLOC4, 256, 0, stream>>>(cplx, vw, v4s);
    k3_dec<<<B64, 256, 0, stream>>>(v4s, dw, db, out);
}